// Round 1
// baseline (334.079 us; speedup 1.0000x reference)
//
#include <hip/hip_runtime.h>

// ROI adaptive avg-pool 7x7, direct per-bin summation (no integral image).
// x: [B=8, C=64, H=256, W=256] f32;  rois: [B, S=128, 5] i32 (idx,x1,y1,x2,y2)
// out: [B, S*C, 7, 7] f32, i.e. out[((b*S+s)*C+c)*49 + oy*7+ox]

constexpr int OUT_HW = 7;
constexpr int BINS = OUT_HW * OUT_HW;

__global__ __launch_bounds__(256) void roi_pool(
    const float* __restrict__ x, const int* __restrict__ rois,
    float* __restrict__ out, int S, int C, int H, int W)
{
    const int bs = blockIdx.x;          // b*S + s
    const int b  = bs / S;              // S = 128 (power of two)
    const int* r = rois + bs * 5;
    const int x1 = r[1], y1 = r[2], x2 = r[3], y2 = r[4];
    const int w = x2 - x1, h = y2 - y1;

    // Bin boundary tables, shared by all 64 channels of this roi.
    __shared__ int s_sy[OUT_HW], s_ey[OUT_HW], s_sx[OUT_HW], s_ex[OUT_HW];
    if (threadIdx.x < OUT_HW) {
        const int i = threadIdx.x;
        s_sy[i] = y1 + (i * h) / OUT_HW;
        s_ey[i] = y1 + ((i + 1) * h + OUT_HW - 1) / OUT_HW;
        s_sx[i] = x1 + (i * w) / OUT_HW;
        s_ex[i] = x1 + ((i + 1) * w + OUT_HW - 1) / OUT_HW;
    }
    __syncthreads();

    const float* __restrict__ xb = x + (size_t)b * C * H * W;
    float* __restrict__ ob = out + (size_t)bs * C * BINS;
    const int total = C * BINS;         // 3136

    for (int o = threadIdx.x; o < total; o += 256) {
        const int c  = o / BINS;
        const int rr = o - c * BINS;
        const int oy = rr / OUT_HW;
        const int ox = rr - oy * OUT_HW;
        const int sy = s_sy[oy], ey = s_ey[oy];
        const int sx = s_sx[ox], ex = s_ex[ox];

        const float* __restrict__ p = xb + (size_t)c * H * W;
        float sum = 0.0f;
        for (int yy = sy; yy < ey; ++yy) {
            const float* __restrict__ row = p + yy * W;
            for (int xx = sx; xx < ex; ++xx) sum += row[xx];
        }
        ob[o] = sum / (float)((ey - sy) * (ex - sx));
    }
}

extern "C" void kernel_launch(void* const* d_in, const int* in_sizes, int n_in,
                              void* d_out, int out_size, void* d_ws, size_t ws_size,
                              hipStream_t stream) {
    const float* x    = (const float*)d_in[0];
    const int*   rois = (const int*)d_in[1];
    float*       out  = (float*)d_out;
    const int B = 8, S = 128, C = 64, H = 256, W = 256;
    roi_pool<<<dim3(B * S), dim3(256), 0, stream>>>(x, rois, out, S, C, H, W);
}